// Round 4
// baseline (837.480 us; speedup 1.0000x reference)
//
#include <hip/hip_runtime.h>
#include <math.h>

#define NB 8
#define NC 256
#define HI 128
#define WI 256
#define HO 32
#define WO 64
#define NN 2048              // HO*WO
#define IGN 19
#define INV_TAU (1.0f/0.07f)
#define PAD 260              // 260 dwords = 1040 B, 16B-aligned, 4-mod-32 banks

// ---------------------------------------------------------------------------
// K1: bilinear 4x downsample. scale=4 exactly => out = 0.25*(x[4i+1,4j+1] +
// x[4i+1,4j+2] + x[4i+2,4j+1] + x[4i+2,4j+2]). Write G[b][c][n] (n contiguous).
__global__ void k_resize(const float* __restrict__ x, float* __restrict__ G) {
    int t = blockIdx.x * 256 + threadIdx.x;     // 0 .. NB*NC*NN (2^22)
    int j = t & 63;
    int i = (t >> 6) & 31;
    int c = (t >> 11) & 255;
    int b = t >> 19;
    const float* p = x + ((((size_t)b*NC + c)*HI + (4*i+1))*WI + (4*j+1));
    float v = 0.25f * (p[0] + p[1] + p[WI] + p[WI+1]);
    G[((size_t)b*NC + c)*NN + i*64 + j] = v;
}

// ---------------------------------------------------------------------------
// K2: nearest labels + per-batch histogram (den[n] = hist[lab[n]]).
__global__ void k_labels(const int* __restrict__ lab, int* __restrict__ L,
                         int* __restrict__ hist) {
    int b = blockIdx.x;
    __shared__ int h[20];
    if (threadIdx.x < 20) h[threadIdx.x] = 0;
    __syncthreads();
    for (int n = threadIdx.x; n < NN; n += 256) {
        int i = n >> 6, j = n & 63;
        int v = lab[((size_t)b*HI + 4*i)*WI + 4*j];
        L[b*NN + n] = v;
        atomicAdd(&h[v], 1);
    }
    __syncthreads();
    if (threadIdx.x < 20) hist[b*20 + threadIdx.x] = h[threadIdx.x];
}

// ---------------------------------------------------------------------------
// K3: inverse L2 norms over C. G is [b][c][n] so reads are coalesced in n.
__global__ void k_norm(const float* __restrict__ G, float* __restrict__ invn) {
    int t = blockIdx.x * 256 + threadIdx.x;   // 0 .. NB*NN
    int b = t >> 11, n = t & 2047;
    const float* p = G + (size_t)b*NC*NN + n;
    float s = 0.f;
    #pragma unroll 8
    for (int c = 0; c < NC; c++) { float v = p[c*NN]; s += v*v; }
    invn[t] = 1.0f / fmaxf(sqrtf(s), 1e-12f);
}

// ---------------------------------------------------------------------------
// K4: main. Per block: one batch b (blockIdx&7 -> XCD-local L2), 32 rows.
// Stream all 64 column tiles; online softmax (m,s) + masked logit sum per row.
// rowval[b][n] = valid ? LSE - msum/den : 0
__global__ __launch_bounds__(256, 2)
void k_main(const float* __restrict__ G, const float* __restrict__ invn,
            const int* __restrict__ L, const int* __restrict__ hist,
            float* __restrict__ rowval) {
    int b    = blockIdx.x & 7;
    int tile = blockIdx.x >> 3;
    int n0   = tile * 32;
    __shared__ float Asm[32][PAD];
    __shared__ float Bsm[32][PAD];
    __shared__ int   labB[32];
    const float* Gb   = G + (size_t)b*NC*NN;
    const float* invb = invn + b*NN;
    int tid = threadIdx.x;

    // stage A tile (rows), fold invnorm * 1/tau
    for (int idx = tid; idx < 32*NC; idx += 256) {
        int c = idx >> 5, r = idx & 31;
        Asm[r][c] = Gb[c*NN + n0 + r] * invb[n0 + r] * INV_TAU;
    }
    int tc = tid & 15, tr = tid >> 4;        // 16x16 thread tile, 2x2 blocking
    int labr0 = L[b*NN + n0 + tr];
    int labr1 = L[b*NN + n0 + tr + 16];
    float m0 = -1e30f, m1 = -1e30f;
    float s0 = 0.f, s1 = 0.f, ms0 = 0.f, ms1 = 0.f;

    for (int mt = 0; mt < 64; mt++) {
        int mb = mt * 32;
        // stage B tile (cols), fold invnorm
        for (int idx = tid; idx < 32*NC; idx += 256) {
            int c = idx >> 5, r = idx & 31;
            Bsm[r][c] = Gb[c*NN + mb + r] * invb[mb + r];
        }
        if (tid < 32) labB[tid] = L[b*NN + mb + tid];
        __syncthreads();

        float a00 = 0.f, a01 = 0.f, a10 = 0.f, a11 = 0.f;
        #pragma unroll 8
        for (int k = 0; k < NC/4; k++) {
            float4 va0 = *(const float4*)&Asm[tr     ][k*4];
            float4 va1 = *(const float4*)&Asm[tr + 16][k*4];
            float4 vb0 = *(const float4*)&Bsm[tc     ][k*4];
            float4 vb1 = *(const float4*)&Bsm[tc + 16][k*4];
            a00 += va0.x*vb0.x + va0.y*vb0.y + va0.z*vb0.z + va0.w*vb0.w;
            a01 += va0.x*vb1.x + va0.y*vb1.y + va0.z*vb1.z + va0.w*vb1.w;
            a10 += va1.x*vb0.x + va1.y*vb0.y + va1.z*vb0.z + va1.w*vb0.w;
            a11 += va1.x*vb1.x + va1.y*vb1.y + va1.z*vb1.z + va1.w*vb1.w;
        }
        __syncthreads();

        int lc0 = labB[tc], lc1 = labB[tc + 16];
        // row tr: logits a00 (col mb+tc), a01 (col mb+tc+16)
        {
            float mx = fmaxf(a00, a01);
            float nm = fmaxf(m0, mx);
            s0 = s0 * __expf(m0 - nm) + __expf(a00 - nm) + __expf(a01 - nm);
            m0 = nm;
            if (labr0 != IGN) {
                if (lc0 == labr0) ms0 += a00;
                if (lc1 == labr0) ms0 += a01;
            }
        }
        // row tr+16: logits a10, a11
        {
            float mx = fmaxf(a10, a11);
            float nm = fmaxf(m1, mx);
            s1 = s1 * __expf(m1 - nm) + __expf(a10 - nm) + __expf(a11 - nm);
            m1 = nm;
            if (labr1 != IGN) {
                if (lc0 == labr1) ms1 += a10;
                if (lc1 == labr1) ms1 += a11;
            }
        }
    }

    // reduce (m,s,msum) across the 16 column-threads of each row group
    #pragma unroll
    for (int off = 1; off < 16; off <<= 1) {
        float om, os;
        om = __shfl_xor(m0, off, 16); os = __shfl_xor(s0, off, 16);
        { float nm = fmaxf(m0, om);
          s0 = s0 * expf(m0 - nm) + os * expf(om - nm); m0 = nm; }
        ms0 += __shfl_xor(ms0, off, 16);
        om = __shfl_xor(m1, off, 16); os = __shfl_xor(s1, off, 16);
        { float nm = fmaxf(m1, om);
          s1 = s1 * expf(m1 - nm) + os * expf(om - nm); m1 = nm; }
        ms1 += __shfl_xor(ms1, off, 16);
    }
    if (tc == 0) {
        float out0 = 0.f, out1 = 0.f;
        if (labr0 != IGN) {
            float den = (float)hist[b*20 + labr0];
            out0 = (m0 + logf(s0)) - ms0 / den;
        }
        if (labr1 != IGN) {
            float den = (float)hist[b*20 + labr1];
            out1 = (m1 + logf(s1)) - ms1 / den;
        }
        rowval[b*NN + n0 + tr]      = out0;
        rowval[b*NN + n0 + tr + 16] = out1;
    }
}

// ---------------------------------------------------------------------------
// K5: final reduce. loss = mean_b( sum_n rowval / max(cnt_valid,1) )
__global__ void k_final(const float* __restrict__ rowval,
                        const int* __restrict__ hist, float* __restrict__ out) {
    __shared__ float red[4];
    int tid = threadIdx.x;
    float loss = 0.f;
    for (int b = 0; b < NB; b++) {
        float s = 0.f;
        for (int n = tid; n < NN; n += 256) s += rowval[b*NN + n];
        #pragma unroll
        for (int off = 32; off >= 1; off >>= 1) s += __shfl_down(s, off, 64);
        if ((tid & 63) == 0) red[tid >> 6] = s;
        __syncthreads();
        if (tid == 0) {
            float tot = red[0] + red[1] + red[2] + red[3];
            int cnt = NN - hist[b*20 + IGN];
            float isum = (cnt == 0) ? 1.f : (float)cnt;
            loss += tot / isum;
        }
        __syncthreads();
    }
    if (tid == 0) out[0] = loss / (float)NB;
}

// ---------------------------------------------------------------------------
extern "C" void kernel_launch(void* const* d_in, const int* in_sizes, int n_in,
                              void* d_out, int out_size, void* d_ws, size_t ws_size,
                              hipStream_t stream) {
    const float* x  = (const float*)d_in[0];
    const int* lab  = (const int*)d_in[1];
    float* out      = (float*)d_out;
    char* ws        = (char*)d_ws;

    const size_t G_BYTES = (size_t)NB*NC*NN*4;       // 16 MiB
    float* G      = (float*)ws;
    float* invn   = (float*)(ws + G_BYTES);
    float* rowval = (float*)(ws + G_BYTES + 65536);
    int*   L      = (int*)  (ws + G_BYTES + 2*65536);
    int*   hist   = (int*)  (ws + G_BYTES + 3*65536);

    k_resize<<<NB*NC*NN/256, 256, 0, stream>>>(x, G);
    k_labels<<<NB, 256, 0, stream>>>(lab, L, hist);
    k_norm  <<<NB*NN/256, 256, 0, stream>>>(G, invn);
    k_main  <<<NB*(NN/32), 256, 0, stream>>>(G, invn, L, hist, rowval);
    k_final <<<1, 256, 0, stream>>>(rowval, hist, out);
}

// Round 5
// 758.552 us; speedup vs baseline: 1.1041x; 1.1041x over previous
//
#include <hip/hip_runtime.h>
#include <math.h>

#define NB 8
#define NC 256
#define HI 128
#define WI 256
#define NN 2048              // 32*64 output pixels
#define IGN 19
#define INV_TAU (1.0f/0.07f)
#define KC 128               // K-chunk (channels per LDS phase)
#define TM 64                // rows per block
#define TW 64                // streamed col tile

// ---------------------------------------------------------------------------
// K1: bilinear 4x downsample == 0.25*(x[4i+1,4j+1]+x[4i+1,4j+2]+x[4i+2,4j+1]
// +x[4i+2,4j+2]). float4 loads (cols 4j..4j+3, use .y/.z). G layout [b][c][n].
__global__ void k_resize(const float* __restrict__ x, float* __restrict__ G) {
    int t = blockIdx.x * 256 + threadIdx.x;     // 0 .. NB*NC*NN
    int j = t & 63;
    int i = (t >> 6) & 31;
    int c = (t >> 11) & 255;
    int b = t >> 19;
    const float* row = x + ((((size_t)b*NC + c)*HI + (4*i+1))*WI + 4*j);
    float4 r0 = *(const float4*)row;            // 16B aligned: 4j*4B
    float4 r1 = *(const float4*)(row + WI);
    G[((size_t)b*NC + c)*NN + i*64 + j] = 0.25f*(r0.y + r0.z + r1.y + r1.z);
}

// ---------------------------------------------------------------------------
// K2: nearest labels + per-batch histogram (den[n] = hist[lab[n]]).
__global__ void k_labels(const int* __restrict__ lab, int* __restrict__ L,
                         int* __restrict__ hist) {
    int b = blockIdx.x;
    __shared__ int h[20];
    if (threadIdx.x < 20) h[threadIdx.x] = 0;
    __syncthreads();
    for (int n = threadIdx.x; n < NN; n += 256) {
        int i = n >> 6, j = n & 63;
        int v = lab[((size_t)b*HI + 4*i)*WI + 4*j];
        L[b*NN + n] = v;
        atomicAdd(&h[v], 1);
    }
    __syncthreads();
    if (threadIdx.x < 20) hist[b*20 + threadIdx.x] = h[threadIdx.x];
}

// ---------------------------------------------------------------------------
// K3: inverse L2 norms over C (coalesced in n per channel step).
__global__ void k_norm(const float* __restrict__ G, float* __restrict__ invn) {
    int t = blockIdx.x * 256 + threadIdx.x;   // 0 .. NB*NN
    int b = t >> 11, n = t & 2047;
    const float* p = G + (size_t)b*NC*NN + n;
    float s = 0.f;
    #pragma unroll 8
    for (int c = 0; c < NC; c++) { float v = p[c*NN]; s += v*v; }
    invn[t] = 1.0f / fmaxf(sqrtf(s), 1e-12f);
}

// ---------------------------------------------------------------------------
// K4: main GEMM + online softmax. 64x64 tile, 16x16 threads, 4x4 per thread.
// LDS layout [k][row], row-quad XOR-swizzled: elem (k,r) at
//   k*64 + ((r>>2 ^ (k&15))<<2) + (r&3).
// A-reads (4 addrs/instr) conflict-free; B-reads 2-way (free). 64 KB static
// LDS total -> 2 blocks/CU.
__global__ __launch_bounds__(256, 2)
void k_main(const float* __restrict__ G, const float* __restrict__ invn,
            const int* __restrict__ L, const int* __restrict__ hist,
            float* __restrict__ rowval) {
    int b    = blockIdx.x & 7;                // batch -> XCD-local L2
    int tile = blockIdx.x >> 3;
    int n0   = tile * TM;
    __shared__ float Asm[KC*64];              // 32 KB
    __shared__ float Bsm[KC*64];              // 32 KB
    const float* Gb   = G + (size_t)b*NC*NN;
    const float* invb = invn + b*NN;
    const int*   Lb   = L + b*NN;
    int tid = threadIdx.x;
    int tx = tid & 15, ty = tid >> 4;         // col group / row group

    int4 lr4 = *(const int4*)&Lb[n0 + ty*4];
    int lr[4] = {lr4.x, lr4.y, lr4.z, lr4.w};

    float m[4], s[4], ms[4];
    #pragma unroll
    for (int i = 0; i < 4; i++) { m[i] = -1e30f; s[i] = 0.f; ms[i] = 0.f; }

    for (int mt = 0; mt < NN/TW; mt++) {
        int mb = mt * TW;
        float acc[4][4];
        #pragma unroll
        for (int i = 0; i < 4; i++)
            #pragma unroll
            for (int j = 0; j < 4; j++) acc[i][j] = 0.f;

        for (int h = 0; h < 2; h++) {
            __syncthreads();                  // protect LDS from prev compute
            // stage A-half (rows, fold invnorm*1/tau) and B-half (cols)
            for (int u = tid; u < KC*16; u += 256) {
                int cc = u >> 4, rq = u & 15;
                int c  = h*KC + cc;
                int sw = cc*64 + ((rq ^ (cc & 15)) << 2);
                float4 va = *(const float4*)&Gb[(size_t)c*NN + n0 + rq*4];
                float4 ia = *(const float4*)&invb[n0 + rq*4];
                va.x *= ia.x * INV_TAU; va.y *= ia.y * INV_TAU;
                va.z *= ia.z * INV_TAU; va.w *= ia.w * INV_TAU;
                *(float4*)&Asm[sw] = va;
                float4 vb = *(const float4*)&Gb[(size_t)c*NN + mb + rq*4];
                float4 ib = *(const float4*)&invb[mb + rq*4];
                vb.x *= ib.x; vb.y *= ib.y; vb.z *= ib.z; vb.w *= ib.w;
                *(float4*)&Bsm[sw] = vb;
            }
            __syncthreads();

            #pragma unroll 16
            for (int kk = 0; kk < KC; kk++) {
                float4 a4 = *(const float4*)&Asm[kk*64 + ((ty ^ (kk & 15)) << 2)];
                float4 b4 = *(const float4*)&Bsm[kk*64 + ((tx ^ (kk & 15)) << 2)];
                acc[0][0] += a4.x*b4.x; acc[0][1] += a4.x*b4.y;
                acc[0][2] += a4.x*b4.z; acc[0][3] += a4.x*b4.w;
                acc[1][0] += a4.y*b4.x; acc[1][1] += a4.y*b4.y;
                acc[1][2] += a4.y*b4.z; acc[1][3] += a4.y*b4.w;
                acc[2][0] += a4.z*b4.x; acc[2][1] += a4.z*b4.y;
                acc[2][2] += a4.z*b4.z; acc[2][3] += a4.z*b4.w;
                acc[3][0] += a4.w*b4.x; acc[3][1] += a4.w*b4.y;
                acc[3][2] += a4.w*b4.z; acc[3][3] += a4.w*b4.w;
            }
        }

        // online softmax + masked logit sum, 4 rows x 4 cols
        int4 lc4 = *(const int4*)&Lb[mb + tx*4];
        int lc[4] = {lc4.x, lc4.y, lc4.z, lc4.w};
        #pragma unroll
        for (int i = 0; i < 4; i++) {
            float mx = fmaxf(fmaxf(acc[i][0], acc[i][1]),
                             fmaxf(acc[i][2], acc[i][3]));
            float nm = fmaxf(m[i], mx);
            s[i] = s[i]*__expf(m[i]-nm)
                 + __expf(acc[i][0]-nm) + __expf(acc[i][1]-nm)
                 + __expf(acc[i][2]-nm) + __expf(acc[i][3]-nm);
            m[i] = nm;
            #pragma unroll
            for (int j = 0; j < 4; j++)
                ms[i] += (lc[j] == lr[i]) ? acc[i][j] : 0.f;
        }
    }

    // reduce (m,s,ms) across the 16 column-threads of each row group
    #pragma unroll
    for (int i = 0; i < 4; i++) {
        #pragma unroll
        for (int off = 1; off < 16; off <<= 1) {
            float om = __shfl_xor(m[i], off, 16);
            float os = __shfl_xor(s[i], off, 16);
            float nm = fmaxf(m[i], om);
            s[i] = s[i]*expf(m[i]-nm) + os*expf(om-nm);
            m[i] = nm;
            ms[i] += __shfl_xor(ms[i], off, 16);
        }
    }
    if (tx == 0) {
        float o[4];
        #pragma unroll
        for (int i = 0; i < 4; i++) {
            o[i] = 0.f;
            if (lr[i] != IGN) {
                float den = (float)hist[b*20 + lr[i]];
                o[i] = (m[i] + logf(s[i])) - ms[i]/den;
            }
        }
        *(float4*)&rowval[b*NN + n0 + ty*4] = make_float4(o[0],o[1],o[2],o[3]);
    }
}

// ---------------------------------------------------------------------------
// K5: final reduce. loss = mean_b( sum_n rowval / max(cnt_valid,1) )
__global__ void k_final(const float* __restrict__ rowval,
                        const int* __restrict__ hist, float* __restrict__ out) {
    __shared__ float red[4];
    int tid = threadIdx.x;
    float loss = 0.f;
    for (int b = 0; b < NB; b++) {
        float s = 0.f;
        for (int n = tid; n < NN; n += 256) s += rowval[b*NN + n];
        #pragma unroll
        for (int off = 32; off >= 1; off >>= 1) s += __shfl_down(s, off, 64);
        if ((tid & 63) == 0) red[tid >> 6] = s;
        __syncthreads();
        if (tid == 0) {
            float tot = red[0] + red[1] + red[2] + red[3];
            int cnt = NN - hist[b*20 + IGN];
            float isum = (cnt == 0) ? 1.f : (float)cnt;
            loss += tot / isum;
        }
        __syncthreads();
    }
    if (tid == 0) out[0] = loss / (float)NB;
}

// ---------------------------------------------------------------------------
extern "C" void kernel_launch(void* const* d_in, const int* in_sizes, int n_in,
                              void* d_out, int out_size, void* d_ws, size_t ws_size,
                              hipStream_t stream) {
    const float* x  = (const float*)d_in[0];
    const int* lab  = (const int*)d_in[1];
    float* out      = (float*)d_out;
    char* ws        = (char*)d_ws;

    const size_t G_BYTES = (size_t)NB*NC*NN*4;       // 16 MiB
    float* G      = (float*)ws;
    float* invn   = (float*)(ws + G_BYTES);
    float* rowval = (float*)(ws + G_BYTES + 65536);
    int*   L      = (int*)  (ws + G_BYTES + 2*65536);
    int*   hist   = (int*)  (ws + G_BYTES + 3*65536);

    k_resize<<<NB*NC*NN/256, 256, 0, stream>>>(x, G);
    k_labels<<<NB, 256, 0, stream>>>(lab, L, hist);
    k_norm  <<<NB*NN/256, 256, 0, stream>>>(G, invn);
    k_main  <<<NB*(NN/TM), 256, 0, stream>>>(G, invn, L, hist, rowval);
    k_final <<<1, 256, 0, stream>>>(rowval, hist, out);
}

// Round 8
// 433.642 us; speedup vs baseline: 1.9313x; 1.7493x over previous
//
#include <hip/hip_runtime.h>
#include <math.h>

#define NB 8
#define NC 256
#define HI 128
#define WI 256
#define NN 2048
#define IGN 19
#define SQT 3.7796447300922722f   // sqrt(1/0.07); folded on BOTH sides: P.P = logit/tau

typedef _Float16 half8  __attribute__((ext_vector_type(8)));
typedef _Float16 half4v __attribute__((ext_vector_type(4)));
typedef float    f32x4  __attribute__((ext_vector_type(4)));

#define MFMA16(a, b, c) __builtin_amdgcn_mfma_f32_16x16x32_f16((a), (b), (c), 0, 0, 0)
#define GLOAD_LDS16(gp, lp) __builtin_amdgcn_global_load_lds( \
    (const __attribute__((address_space(1))) void*)(gp), \
    (__attribute__((address_space(3))) void*)(lp), 16, 0, 0)

// ---------------------------------------------------------------------------
// K1: bilinear 4x downsample == 0.25*(x[4i+1,4j+1]+x[4i+1,4j+2]+x[4i+2,4j+1]
// +x[4i+2,4j+2]). G layout [b][c][n] fp32 (needed exact for norms).
__global__ void k_resize(const float* __restrict__ x, float* __restrict__ G) {
    int t = blockIdx.x * 256 + threadIdx.x;
    int j = t & 63;
    int i = (t >> 6) & 31;
    int c = (t >> 11) & 255;
    int b = t >> 19;
    const float* row = x + ((((size_t)b*NC + c)*HI + (4*i+1))*WI + 4*j);
    float4 r0 = *(const float4*)row;
    float4 r1 = *(const float4*)(row + WI);
    G[((size_t)b*NC + c)*NN + i*64 + j] = 0.25f*(r0.y + r0.z + r1.y + r1.z);
}

// ---------------------------------------------------------------------------
// K2: nearest labels + per-batch histogram (den[n] = hist[lab[n]]).
__global__ void k_labels(const int* __restrict__ lab, int* __restrict__ L,
                         int* __restrict__ hist) {
    int b = blockIdx.x;
    __shared__ int h[20];
    if (threadIdx.x < 20) h[threadIdx.x] = 0;
    __syncthreads();
    for (int n = threadIdx.x; n < NN; n += 256) {
        int i = n >> 6, j = n & 63;
        int v = lab[((size_t)b*HI + 4*i)*WI + 4*j];
        L[b*NN + n] = v;
        atomicAdd(&h[v], 1);
    }
    __syncthreads();
    if (threadIdx.x < 20) hist[b*20 + threadIdx.x] = h[threadIdx.x];
}

// ---------------------------------------------------------------------------
// K3: inverse L2 norms over C.
__global__ void k_norm(const float* __restrict__ G, float* __restrict__ invn) {
    int t = blockIdx.x * 256 + threadIdx.x;
    int b = t >> 11, n = t & 2047;
    const float* p = G + (size_t)b*NC*NN + n;
    float s = 0.f;
    #pragma unroll 8
    for (int c = 0; c < NC; c++) { float v = p[c*NN]; s += v*v; }
    invn[t] = 1.0f / fmaxf(sqrtf(s), 1e-12f);
}

// ---------------------------------------------------------------------------
// K3b: pack+transpose: P[n][k] = G[k][n]*inv[n]*SQT split into f16 hi + lo
// planes (hi = f16(v), lo = f16(v - hi); v - hi exact in fp32).
__global__ void k_pack(const float* __restrict__ G, const float* __restrict__ invn,
                       _Float16* __restrict__ Phi, _Float16* __restrict__ Plo) {
    int blk = blockIdx.x;
    int b  = blk & 7;
    int t  = blk >> 3;              // 0..127
    int c0 = (t >> 5) * 64;
    int n0 = (t & 31) * 64;
    __shared__ float T[64][65];
    const float* Gb = G + (size_t)b*NC*NN;
    const float* invb = invn + b*NN;
    int tid = threadIdx.x;
    #pragma unroll
    for (int it = 0; it < 4; it++) {
        int idx = it*256 + tid;
        int cl = idx >> 4, nq = idx & 15;
        float4 v = *(const float4*)&Gb[(size_t)(c0+cl)*NN + n0 + nq*4];
        T[cl][nq*4+0]=v.x; T[cl][nq*4+1]=v.y; T[cl][nq*4+2]=v.z; T[cl][nq*4+3]=v.w;
    }
    __syncthreads();
    #pragma unroll
    for (int it = 0; it < 4; it++) {
        int idx = it*256 + tid;
        int nl = idx >> 4, cq = idx & 15;
        float s = invb[n0+nl] * SQT;
        half4v hh, hl;
        #pragma unroll
        for (int e = 0; e < 4; e++) {
            float v = T[cq*4+e][nl] * s;
            _Float16 h = (_Float16)v;
            hh[e] = h;
            hl[e] = (_Float16)(v - (float)h);
        }
        size_t o = ((size_t)(b*NN + n0 + nl))*NC + c0 + cq*4;
        *(half4v*)&Phi[o] = hh;
        *(half4v*)&Plo[o] = hl;
    }
}

// ---------------------------------------------------------------------------
// K4: MFMA Gram + online softmax. Block: 64 rows x streamed 64-col tiles.
// 4 waves 2x2; wave tile 32x32 = 2x2 16x16x32_f16 MFMA x 3 split terms.
// A hi/lo in registers (128 VGPR); B dbuf in LDS via global_load_lds with
// inverse-swizzled per-lane SOURCE (linear LDS dest), reads swizzled
// kb^(col&7) -> conflict-free ds_read_b128.
__global__ __launch_bounds__(256, 1)
void k_main(const _Float16* __restrict__ Phi, const _Float16* __restrict__ Plo,
            const int* __restrict__ L, const int* __restrict__ hist,
            float* __restrict__ rowval) {
    int b    = blockIdx.x & 7;       // batch -> XCD-local L2
    int tile = blockIdx.x >> 3;
    int n0   = tile * 64;
    const _Float16* PhiB = Phi + (size_t)b*NN*NC;
    const _Float16* PloB = Plo + (size_t)b*NN*NC;
    const int* Lb = L + b*NN;

    __shared__ _Float16 BhS[2][64*NC];       // 64 KB
    __shared__ _Float16 BlS[2][64*NC];       // 64 KB
    __shared__ float smM[2][64], smS[2][64], smMS[2][64];

    int tid  = threadIdx.x;
    int lane = tid & 63;
    int w    = tid >> 6;
    int wr   = w >> 1, wc = w & 1;
    int lr16 = lane & 15, lq = lane >> 4;

    // ---- A fragments (rows n0+wr*32..+31), hi and lo, K=256 in 8 steps
    half8 Ah[2][8], Al[2][8];
    #pragma unroll
    for (int t = 0; t < 2; t++) {
        int row = n0 + wr*32 + t*16 + lr16;
        const _Float16* pa = PhiB + (size_t)row*NC + lq*8;
        const _Float16* pb = PloB + (size_t)row*NC + lq*8;
        #pragma unroll
        for (int s = 0; s < 8; s++) {
            Ah[t][s] = *(const half8*)(pa + s*32);
            Al[t][s] = *(const half8*)(pb + s*32);
        }
    }
    int4 lr4[2];
    #pragma unroll
    for (int t = 0; t < 2; t++)
        lr4[t] = *(const int4*)&Lb[n0 + wr*32 + t*16 + lq*4];

    float sm_m[8], sm_s[8], sm_ms[8];
    #pragma unroll
    for (int i = 0; i < 8; i++) { sm_m[i] = -1e30f; sm_s[i] = 0.f; sm_ms[i] = 0.f; }

    // stage col-tile mt into buffer buf (pure copy, Phi/Plo pre-split)
    auto stage = [&](int mt, int buf) {
        int mb = mt * 64;
        #pragma unroll
        for (int it = 0; it < 8; it++) {
            int ch  = w*512 + it*64 + lane;          // 2048 16B-chunks/plane
            int col = ch >> 5, kbs = ch & 31;
            int src = (mb + col)*NC + ((kbs ^ (col & 7)) << 3);
            int dst = (w*512 + it*64) * 8;           // wave-uniform halves idx
            GLOAD_LDS16(PhiB + src, &BhS[buf][dst]);
            GLOAD_LDS16(PloB + src, &BlS[buf][dst]);
        }
    };

    auto compute = [&](int mt, int buf) {
        int mb  = mt * 64;
        int cl0 = wc*32 + lr16;
        int cl1 = cl0 + 16;
        int lc0 = Lb[mb + cl0];
        int lc1 = Lb[mb + cl1];
        f32x4 acc[2][2];
        #pragma unroll
        for (int t = 0; t < 2; t++)
            #pragma unroll
            for (int u = 0; u < 2; u++) acc[t][u] = (f32x4){0.f,0.f,0.f,0.f};

        #pragma unroll
        for (int s = 0; s < 8; s++) {
            int x0 = ((s*4 + lq) ^ (lr16 & 7)) << 3;   // swizzled 16B slot
            half8 B0h = *(const half8*)&BhS[buf][cl0*NC + x0];
            half8 B1h = *(const half8*)&BhS[buf][cl1*NC + x0];
            half8 B0l = *(const half8*)&BlS[buf][cl0*NC + x0];
            half8 B1l = *(const half8*)&BlS[buf][cl1*NC + x0];
            #pragma unroll
            for (int t = 0; t < 2; t++) {
                acc[t][0] = MFMA16(Ah[t][s], B0h, acc[t][0]);
                acc[t][0] = MFMA16(Ah[t][s], B0l, acc[t][0]);
                acc[t][0] = MFMA16(Al[t][s], B0h, acc[t][0]);
                acc[t][1] = MFMA16(Ah[t][s], B1h, acc[t][1]);
                acc[t][1] = MFMA16(Ah[t][s], B1l, acc[t][1]);
                acc[t][1] = MFMA16(Al[t][s], B1h, acc[t][1]);
            }
        }
        // online softmax + masked logit sum (C/D: col=lane&15, row=lq*4+r)
        #pragma unroll
        for (int t = 0; t < 2; t++) {
            int lrv[4] = {lr4[t].x, lr4[t].y, lr4[t].z, lr4[t].w};
            #pragma unroll
            for (int r = 0; r < 4; r++) {
                float v0 = acc[t][0][r], v1 = acc[t][1][r];
                int i = t*4 + r;
                float nm = fmaxf(sm_m[i], fmaxf(v0, v1));
                sm_s[i] = sm_s[i]*__expf(sm_m[i]-nm) + __expf(v0-nm) + __expf(v1-nm);
                sm_m[i] = nm;
                sm_ms[i] += (lc0 == lrv[r] ? v0 : 0.f) + (lc1 == lrv[r] ? v1 : 0.f);
            }
        }
    };

    stage(0, 0);
    __syncthreads();                         // vmcnt(0) drain -> buf0 ready
    for (int mt = 0; mt < 32; mt++) {
        int cur = mt & 1;
        if (mt + 1 < 32) stage(mt + 1, cur ^ 1);   // flies during compute
        compute(mt, cur);
        __syncthreads();                     // drains stage loads; buf swap safe
    }

    // reduce across 16 column-lanes of each row
    #pragma unroll
    for (int i = 0; i < 8; i++) {
        #pragma unroll
        for (int off = 1; off < 16; off <<= 1) {
            float om  = __shfl_xor(sm_m[i], off, 16);
            float os  = __shfl_xor(sm_s[i], off, 16);
            float oms = __shfl_xor(sm_ms[i], off, 16);
            float nm = fmaxf(sm_m[i], om);
            sm_s[i] = sm_s[i]*__expf(sm_m[i]-nm) + os*__expf(om-nm);
            sm_m[i] = nm;
            sm_ms[i] += oms;
        }
    }
    if (lr16 == 0) {
        #pragma unroll
        for (int t = 0; t < 2; t++)
            #pragma unroll
            for (int r = 0; r < 4; r++) {
                int rl = wr*32 + t*16 + lq*4 + r;
                smM[wc][rl]  = sm_m[t*4+r];
                smS[wc][rl]  = sm_s[t*4+r];
                smMS[wc][rl] = sm_ms[t*4+r];
            }
    }
    __syncthreads();
    if (tid < 64) {                          // merge the two col-half waves
        float m0 = smM[0][tid], m1 = smM[1][tid];
        float nm = fmaxf(m0, m1);
        float ss = smS[0][tid]*__expf(m0-nm) + smS[1][tid]*__expf(m1-nm);
        float msv = smMS[0][tid] + smMS[1][tid];
        int lrv = Lb[n0 + tid];
        float o = 0.f;
        if (lrv != IGN) {
            float den = (float)hist[b*20 + lrv];
            o = (nm + logf(ss)) - msv/den;
        }
        rowval[b*NN + n0 + tid] = o;
    }
}

// ---------------------------------------------------------------------------
// K5: final reduce. loss = mean_b( sum_n rowval / max(cnt_valid,1) )
__global__ void k_final(const float* __restrict__ rowval,
                        const int* __restrict__ hist, float* __restrict__ out) {
    __shared__ float red[4];
    int tid = threadIdx.x;
    float loss = 0.f;
    for (int b = 0; b < NB; b++) {
        float s = 0.f;
        for (int n = tid; n < NN; n += 256) s += rowval[b*NN + n];
        #pragma unroll
        for (int off = 32; off >= 1; off >>= 1) s += __shfl_down(s, off, 64);
        if ((tid & 63) == 0) red[tid >> 6] = s;
        __syncthreads();
        if (tid == 0) {
            float tot = red[0] + red[1] + red[2] + red[3];
            int cnt = NN - hist[b*20 + IGN];
            float isum = (cnt == 0) ? 1.f : (float)cnt;
            loss += tot / isum;
        }
        __syncthreads();
    }
    if (tid == 0) out[0] = loss / (float)NB;
}

// ---------------------------------------------------------------------------
extern "C" void kernel_launch(void* const* d_in, const int* in_sizes, int n_in,
                              void* d_out, int out_size, void* d_ws, size_t ws_size,
                              hipStream_t stream) {
    const float* x  = (const float*)d_in[0];
    const int* lab  = (const int*)d_in[1];
    float* out      = (float*)d_out;
    char* ws        = (char*)d_ws;

    const size_t G_BYTES = (size_t)NB*NC*NN*4;       // 16 MiB
    const size_t P_BYTES = (size_t)NB*NC*NN*2;       // 8 MiB each plane
    float*     G      = (float*)ws;
    _Float16*  Phi    = (_Float16*)(ws + G_BYTES);
    _Float16*  Plo    = (_Float16*)(ws + G_BYTES + P_BYTES);
    float*     invn   = (float*)(ws + G_BYTES + 2*P_BYTES);
    float*     rowval = (float*)(ws + G_BYTES + 2*P_BYTES + 65536);
    int*       L      = (int*)  (ws + G_BYTES + 2*P_BYTES + 2*65536);
    int*       hist   = (int*)  (ws + G_BYTES + 2*P_BYTES + 3*65536);

    k_resize<<<NB*NC*NN/256, 256, 0, stream>>>(x, G);
    k_labels<<<NB, 256, 0, stream>>>(lab, L, hist);
    k_norm  <<<NB*NN/256, 256, 0, stream>>>(G, invn);
    k_pack  <<<NB*4*32, 256, 0, stream>>>(G, invn, Phi, Plo);
    k_main  <<<NB*(NN/64), 256, 0, stream>>>(Phi, Plo, L, hist, rowval);
    k_final <<<1, 256, 0, stream>>>(rowval, hist, out);
}

// Round 9
// 397.214 us; speedup vs baseline: 2.1084x; 1.0917x over previous
//
#include <hip/hip_runtime.h>
#include <math.h>

#define NB 8
#define NC 256
#define HI 128
#define WI 256
#define NN 2048
#define IGN 19
#define SQT 3.7796447300922722f   // sqrt(1/0.07); folded on BOTH sides: P.P = logit/tau

typedef _Float16 half8  __attribute__((ext_vector_type(8)));
typedef float    f32x4  __attribute__((ext_vector_type(4)));

#define MFMA16(a, b, c) __builtin_amdgcn_mfma_f32_16x16x32_f16((a), (b), (c), 0, 0, 0)
#define GLOAD_LDS16(gp, lp) __builtin_amdgcn_global_load_lds( \
    (const __attribute__((address_space(1))) void*)(gp), \
    (__attribute__((address_space(3))) void*)(lp), 16, 0, 0)

// ---------------------------------------------------------------------------
// K2: nearest labels + per-batch histogram; also zeroes accB[b] (used by
// k_main's atomic loss accumulation; safe by stream ordering).
__global__ void k_labels(const int* __restrict__ lab, int* __restrict__ L,
                         int* __restrict__ hist, float* __restrict__ accB) {
    int b = blockIdx.x;
    __shared__ int h[20];
    if (threadIdx.x < 20) h[threadIdx.x] = 0;
    if (threadIdx.x == 0) accB[b] = 0.f;
    __syncthreads();
    for (int n = threadIdx.x; n < NN; n += 256) {
        int i = n >> 6, j = n & 63;
        int v = lab[((size_t)b*HI + 4*i)*WI + 4*j];
        L[b*NN + n] = v;
        atomicAdd(&h[v], 1);
    }
    __syncthreads();
    if (threadIdx.x < 20) hist[b*20 + threadIdx.x] = h[threadIdx.x];
}

// ---------------------------------------------------------------------------
// K_fuse: bilinear 4x downsample + L2-norm over C + split-f16 pack, one pass.
// Block (b,i): 64 output pixels (row i), all 256 channels.
//   phase1: v = 0.25*(x[4i+1,4j+1]+x[4i+1,4j+2]+x[4i+2,4j+1]+x[4i+2,4j+2])
//           into LDS V[c][j]; per-thread partial sum of v^2 over its c-range.
//   phase2: per-pixel norm reduce; invl[j] = SQT / max(||v||,1e-12).
//   phase3: Phi/Plo[b][n][c] = split-f16(v * invl), 16B coalesced writes.
__global__ __launch_bounds__(512, 1)
void k_fuse(const float* __restrict__ x, _Float16* __restrict__ Phi,
            _Float16* __restrict__ Plo) {
    int blk = blockIdx.x;
    int b = blk & 7;                 // batch -> XCD-local L2
    int i = blk >> 3;                // 0..31
    __shared__ float V[NC][65];      // +1 pad: phase3 column reads
    __shared__ float nred[8][64];
    __shared__ float invl[64];
    int tid = threadIdx.x;
    int tc  = tid >> 6;              // wave 0..7
    int j   = tid & 63;

    float acc = 0.f;
    #pragma unroll 4
    for (int cc = 0; cc < 32; cc++) {
        int c = tc*32 + cc;
        const float* row = x + ((((size_t)b*NC + c)*HI + (4*i+1))*WI + 4*j);
        float4 r0 = *(const float4*)row;
        float4 r1 = *(const float4*)(row + WI);
        float v = 0.25f*(r0.y + r0.z + r1.y + r1.z);
        V[c][j] = v;
        acc += v*v;
    }
    nred[tc][j] = acc;
    __syncthreads();
    if (tid < 64) {
        float s = 0.f;
        #pragma unroll
        for (int q = 0; q < 8; q++) s += nred[q][tid];
        invl[tid] = (1.0f / fmaxf(sqrtf(s), 1e-12f)) * SQT;
    }
    __syncthreads();

    #pragma unroll
    for (int it = 0; it < 4; it++) {
        int idx = it*512 + tid;
        int nl = idx >> 5;           // pixel 0..63
        int ch = idx & 31;           // 8-channel chunk
        float sc = invl[nl];
        half8 hh, hl;
        #pragma unroll
        for (int e = 0; e < 8; e++) {
            float v = V[ch*8+e][nl] * sc;
            _Float16 h = (_Float16)v;
            hh[e] = h;
            hl[e] = (_Float16)(v - (float)h);
        }
        size_t o = ((size_t)(b*NN + i*64 + nl))*NC + ch*8;
        *(half8*)&Phi[o] = hh;
        *(half8*)&Plo[o] = hl;
    }
}

// ---------------------------------------------------------------------------
// K4: MFMA Gram + online softmax (unchanged structure from round 8); tail now
// block-reduces the 64 row losses and atomicAdds into accB[b].
__global__ __launch_bounds__(256, 1)
void k_main(const _Float16* __restrict__ Phi, const _Float16* __restrict__ Plo,
            const int* __restrict__ L, const int* __restrict__ hist,
            float* __restrict__ accB) {
    int b    = blockIdx.x & 7;       // batch -> XCD-local L2
    int tile = blockIdx.x >> 3;
    int n0   = tile * 64;
    const _Float16* PhiB = Phi + (size_t)b*NN*NC;
    const _Float16* PloB = Plo + (size_t)b*NN*NC;
    const int* Lb = L + b*NN;

    __shared__ _Float16 BhS[2][64*NC];       // 64 KB
    __shared__ _Float16 BlS[2][64*NC];       // 64 KB
    __shared__ float smM[2][64], smS[2][64], smMS[2][64];

    int tid  = threadIdx.x;
    int lane = tid & 63;
    int w    = tid >> 6;
    int wr   = w >> 1, wc = w & 1;
    int lr16 = lane & 15, lq = lane >> 4;

    // ---- A fragments (rows n0+wr*32..+31), hi and lo, K=256 in 8 steps
    half8 Ah[2][8], Al[2][8];
    #pragma unroll
    for (int t = 0; t < 2; t++) {
        int row = n0 + wr*32 + t*16 + lr16;
        const _Float16* pa = PhiB + (size_t)row*NC + lq*8;
        const _Float16* pb = PloB + (size_t)row*NC + lq*8;
        #pragma unroll
        for (int s = 0; s < 8; s++) {
            Ah[t][s] = *(const half8*)(pa + s*32);
            Al[t][s] = *(const half8*)(pb + s*32);
        }
    }
    int4 lr4[2];
    #pragma unroll
    for (int t = 0; t < 2; t++)
        lr4[t] = *(const int4*)&Lb[n0 + wr*32 + t*16 + lq*4];

    float sm_m[8], sm_s[8], sm_ms[8];
    #pragma unroll
    for (int i = 0; i < 8; i++) { sm_m[i] = -1e30f; sm_s[i] = 0.f; sm_ms[i] = 0.f; }

    auto stage = [&](int mt, int buf) {
        int mb = mt * 64;
        #pragma unroll
        for (int it = 0; it < 8; it++) {
            int ch  = w*512 + it*64 + lane;          // 2048 16B-chunks/plane
            int col = ch >> 5, kbs = ch & 31;
            int src = (mb + col)*NC + ((kbs ^ (col & 7)) << 3);
            int dst = (w*512 + it*64) * 8;           // wave-uniform halves idx
            GLOAD_LDS16(PhiB + src, &BhS[buf][dst]);
            GLOAD_LDS16(PloB + src, &BlS[buf][dst]);
        }
    };

    auto compute = [&](int mt, int buf) {
        int mb  = mt * 64;
        int cl0 = wc*32 + lr16;
        int cl1 = cl0 + 16;
        int lc0 = Lb[mb + cl0];
        int lc1 = Lb[mb + cl1];
        f32x4 acc[2][2];
        #pragma unroll
        for (int t = 0; t < 2; t++)
            #pragma unroll
            for (int u = 0; u < 2; u++) acc[t][u] = (f32x4){0.f,0.f,0.f,0.f};

        #pragma unroll
        for (int s = 0; s < 8; s++) {
            int x0 = ((s*4 + lq) ^ (lr16 & 7)) << 3;   // swizzled 16B slot
            half8 B0h = *(const half8*)&BhS[buf][cl0*NC + x0];
            half8 B1h = *(const half8*)&BhS[buf][cl1*NC + x0];
            half8 B0l = *(const half8*)&BlS[buf][cl0*NC + x0];
            half8 B1l = *(const half8*)&BlS[buf][cl1*NC + x0];
            #pragma unroll
            for (int t = 0; t < 2; t++) {
                acc[t][0] = MFMA16(Ah[t][s], B0h, acc[t][0]);
                acc[t][0] = MFMA16(Ah[t][s], B0l, acc[t][0]);
                acc[t][0] = MFMA16(Al[t][s], B0h, acc[t][0]);
                acc[t][1] = MFMA16(Ah[t][s], B1h, acc[t][1]);
                acc[t][1] = MFMA16(Ah[t][s], B1l, acc[t][1]);
                acc[t][1] = MFMA16(Al[t][s], B1h, acc[t][1]);
            }
        }
        // online softmax + masked logit sum (C/D: col=lane&15, row=lq*4+r)
        #pragma unroll
        for (int t = 0; t < 2; t++) {
            int lrv[4] = {lr4[t].x, lr4[t].y, lr4[t].z, lr4[t].w};
            #pragma unroll
            for (int r = 0; r < 4; r++) {
                float v0 = acc[t][0][r], v1 = acc[t][1][r];
                int i = t*4 + r;
                float nm = fmaxf(sm_m[i], fmaxf(v0, v1));
                sm_s[i] = sm_s[i]*__expf(sm_m[i]-nm) + __expf(v0-nm) + __expf(v1-nm);
                sm_m[i] = nm;
                sm_ms[i] += (lc0 == lrv[r] ? v0 : 0.f) + (lc1 == lrv[r] ? v1 : 0.f);
            }
        }
    };

    stage(0, 0);
    __syncthreads();                         // vmcnt(0) drain -> buf0 ready
    for (int mt = 0; mt < 32; mt++) {
        int cur = mt & 1;
        if (mt + 1 < 32) stage(mt + 1, cur ^ 1);   // flies during compute
        compute(mt, cur);
        __syncthreads();                     // drains stage loads; buf swap safe
    }

    // reduce across 16 column-lanes of each row
    #pragma unroll
    for (int i = 0; i < 8; i++) {
        #pragma unroll
        for (int off = 1; off < 16; off <<= 1) {
            float om  = __shfl_xor(sm_m[i], off, 16);
            float os  = __shfl_xor(sm_s[i], off, 16);
            float oms = __shfl_xor(sm_ms[i], off, 16);
            float nm = fmaxf(sm_m[i], om);
            sm_s[i] = sm_s[i]*__expf(sm_m[i]-nm) + os*__expf(om-nm);
            sm_m[i] = nm;
            sm_ms[i] += oms;
        }
    }
    if (lr16 == 0) {
        #pragma unroll
        for (int t = 0; t < 2; t++)
            #pragma unroll
            for (int r = 0; r < 4; r++) {
                int rl = wr*32 + t*16 + lq*4 + r;
                smM[wc][rl]  = sm_m[t*4+r];
                smS[wc][rl]  = sm_s[t*4+r];
                smMS[wc][rl] = sm_ms[t*4+r];
            }
    }
    __syncthreads();
    if (tid < 64) {                          // merge col-half waves + row loss
        float m0 = smM[0][tid], m1 = smM[1][tid];
        float nm = fmaxf(m0, m1);
        float ss = smS[0][tid]*__expf(m0-nm) + smS[1][tid]*__expf(m1-nm);
        float msv = smMS[0][tid] + smMS[1][tid];
        int lrv = Lb[n0 + tid];
        float o = 0.f;
        if (lrv != IGN) {
            float den = (float)hist[b*20 + lrv];
            o = (nm + logf(ss)) - msv/den;
        }
        #pragma unroll
        for (int off = 32; off >= 1; off >>= 1) o += __shfl_down(o, off, 64);
        if (tid == 0) atomicAdd(&accB[b], o);
    }
}

// ---------------------------------------------------------------------------
// K5: trivial final combine. loss = mean_b( accB[b] / max(cnt_valid,1) )
__global__ void k_final(const float* __restrict__ accB,
                        const int* __restrict__ hist, float* __restrict__ out) {
    if (threadIdx.x == 0) {
        float loss = 0.f;
        for (int b = 0; b < NB; b++) {
            int cnt = NN - hist[b*20 + IGN];
            float isum = (cnt == 0) ? 1.f : (float)cnt;
            loss += accB[b] / isum;
        }
        out[0] = loss / (float)NB;
    }
}

// ---------------------------------------------------------------------------
extern "C" void kernel_launch(void* const* d_in, const int* in_sizes, int n_in,
                              void* d_out, int out_size, void* d_ws, size_t ws_size,
                              hipStream_t stream) {
    const float* x  = (const float*)d_in[0];
    const int* lab  = (const int*)d_in[1];
    float* out      = (float*)d_out;
    char* ws        = (char*)d_ws;

    const size_t P_BYTES = (size_t)NB*NC*NN*2;       // 8 MiB each plane
    _Float16*  Phi  = (_Float16*)ws;
    _Float16*  Plo  = (_Float16*)(ws + P_BYTES);
    int*       L    = (int*)  (ws + 2*P_BYTES);
    int*       hist = (int*)  (ws + 2*P_BYTES + 65536);
    float*     accB = (float*)(ws + 2*P_BYTES + 65536 + 4096);

    k_labels<<<NB, 256, 0, stream>>>(lab, L, hist, accB);
    k_fuse  <<<NB*32, 512, 0, stream>>>(x, Phi, Plo);
    k_main  <<<NB*(NN/64), 256, 0, stream>>>(Phi, Plo, L, hist, accB);
    k_final <<<1, 64, 0, stream>>>(accB, hist, out);
}